// Round 3
// baseline (358.073 us; speedup 1.0000x reference)
//
#include <hip/hip_runtime.h>
#include <hip/hip_bf16.h>
#include <math.h>

#define L_SEQ   16384
#define C_DIM   256
#define N_BATCH 4
#define N_HEAD  8
#define D_H     32
#define M_ROWS  (N_BATCH * L_SEQ)   // 65536
#define KV_SPLIT 64

typedef unsigned short u16;
typedef unsigned int   u32;
typedef short s16x8 __attribute__((ext_vector_type(8)));
typedef float f32x4 __attribute__((ext_vector_type(4)));

// ---- bf16 helpers (bit-exact bf16->f32; RNE f32->bf16) ----------------------
__device__ __forceinline__ float bf2f(u32 lo16) { return __uint_as_float(lo16 << 16); }
__device__ __forceinline__ u16 f2bf(float f) {
    u32 u = __float_as_uint(f);
    u32 rb = ((u >> 16) & 1u) + 0x7fffu;
    return (u16)((u + rb) >> 16);
}

// ---- async global->LDS, 16B per lane ---------------------------------------
__device__ __forceinline__ void gl_lds16(const u16* g, u16* l) {
    __builtin_amdgcn_global_load_lds(
        (__attribute__((address_space(1))) void*)g,
        (__attribute__((address_space(3))) void*)l, 16, 0, 0);
}

// ---------------------------------------------------------------------------
// f32 -> bf16 bulk convert (8 elems/thread/iter)
// ---------------------------------------------------------------------------
__global__ __launch_bounds__(256)
void f32_to_bf16_k(const float* __restrict__ in, u16* __restrict__ out, int n8)
{
    int i = blockIdx.x * blockDim.x + threadIdx.x;
    int stride = gridDim.x * blockDim.x;
    for (; i < n8; i += stride) {
        float4 f0 = ((const float4*)in)[(size_t)i * 2];
        float4 f1 = ((const float4*)in)[(size_t)i * 2 + 1];
        uint4 o;
        o.x = (u32)f2bf(f0.x) | ((u32)f2bf(f0.y) << 16);
        o.y = (u32)f2bf(f0.z) | ((u32)f2bf(f0.w) << 16);
        o.z = (u32)f2bf(f1.x) | ((u32)f2bf(f1.y) << 16);
        o.w = (u32)f2bf(f1.z) | ((u32)f2bf(f1.w) << 16);
        ((uint4*)out)[i] = o;
    }
}

// ---------------------------------------------------------------------------
// All weight transposes in one kernel. W[K][N] f32 -> Wt[rowoff+n][K] bf16.
// 640 tile-blocks of 32x32: [0,192) Wq/Wk/Wv->wqkvt, [192,256) Wm,
// [256,512) W1, [512,640) W2.
// ---------------------------------------------------------------------------
__global__ __launch_bounds__(256)
void w_prep(const float* __restrict__ Wq, const float* __restrict__ Wk,
            const float* __restrict__ Wv, const float* __restrict__ Wm,
            const float* __restrict__ W1, const float* __restrict__ W2,
            u16* __restrict__ wqkvt, u16* __restrict__ wmt,
            u16* __restrict__ w1t, u16* __restrict__ w2t)
{
    __shared__ float tile[32][33];
    int bt = blockIdx.x;
    const float* src; u16* dst; int K, N, rowoff, tt;
    if (bt < 192)      { int w = bt >> 6; tt = bt & 63;
                         src = (w == 0) ? Wq : (w == 1) ? Wk : Wv;
                         dst = wqkvt; K = 256; N = 256; rowoff = w * 256; }
    else if (bt < 256) { tt = bt - 192; src = Wm; dst = wmt; K = 256; N = 256; rowoff = 0; }
    else if (bt < 512) { tt = bt - 256; src = W1; dst = w1t; K = 512; N = 512; rowoff = 0; }
    else               { tt = bt - 512; src = W2; dst = w2t; K = 512; N = 256; rowoff = 0; }
    int ntx = N >> 5;
    int n0 = (tt % ntx) * 32, k0 = (tt / ntx) * 32;
    int tx = threadIdx.x & 31, ty = threadIdx.x >> 5;
    #pragma unroll
    for (int i = 0; i < 32; i += 8)
        tile[ty + i][tx] = src[(size_t)(k0 + ty + i) * N + n0 + tx];
    __syncthreads();
    #pragma unroll
    for (int i = 0; i < 32; i += 8)
        dst[(size_t)(rowoff + n0 + ty + i) * K + k0 + tx] = f2bf(tile[tx][ty + i]);
}

// ---------------------------------------------------------------------------
// bf16 MFMA GEMM: C[., ldc] = EPI( concat(A1,A2)[M,K] @ Bt^T )
// Bt[N][K] bf16 (transposed). Tile 128x128, BK=32, 4 waves, 4x4 16x16x32 MFMA.
// EPI: 0=none, 1=elu+1, 2=x*escale, 3=relu, 4=qkv(col<512:elu+1 else *escale)
// ---------------------------------------------------------------------------
template<int EPI>
__global__ __launch_bounds__(256)
void gemm_bf16(const u16* __restrict__ A1, const u16* __restrict__ A2,
               int KA, int sA1, int sA2,
               const u16* __restrict__ Bt, int ldb,
               u16* __restrict__ C, int ldc, int K, float escale)
{
    __shared__ __align__(16) u16 As[128 * 32];
    __shared__ __align__(16) u16 Bs[128 * 32];

    const int tid = threadIdx.x;
    const int m0 = blockIdx.y * 128;
    const int n0 = blockIdx.x * 128;
    const int w = tid >> 6, lane = tid & 63;
    const int wr = w >> 1, wc = w & 1;
    const int g = lane >> 4, r = lane & 15;

    f32x4 acc[4][4] = {};

    const int ktiles = K / 32;
    for (int kt = 0; kt < ktiles; ++kt) {
        __syncthreads();
        #pragma unroll
        for (int i = 0; i < 2; ++i) {
            int li  = i * 256 + tid;
            int row = li >> 2, kc = li & 3;
            int kg = kt * 32 + kc * 8;
            const u16* Ap = (kg < KA) ? A1 : A2;
            int stride    = (kg < KA) ? sA1 : sA2;
            int col       = (kg < KA) ? kg  : kg - KA;
            gl_lds16(Ap + (size_t)(m0 + row) * stride + col, &As[li * 8]);
            gl_lds16(Bt + (size_t)(n0 + row) * ldb + kt * 32 + kc * 8, &Bs[li * 8]);
        }
        __syncthreads();

        s16x8 a[4], b[4];
        #pragma unroll
        for (int mi = 0; mi < 4; ++mi)
            a[mi] = *(const s16x8*)&As[(wr * 64 + mi * 16 + r) * 32 + g * 8];
        #pragma unroll
        for (int ni = 0; ni < 4; ++ni)
            b[ni] = *(const s16x8*)&Bs[(wc * 64 + ni * 16 + r) * 32 + g * 8];
        #pragma unroll
        for (int mi = 0; mi < 4; ++mi)
            #pragma unroll
            for (int ni = 0; ni < 4; ++ni)
                asm volatile("v_mfma_f32_16x16x32_bf16 %0, %1, %2, %0"
                             : "+v"(acc[mi][ni]) : "v"(a[mi]), "v"(b[ni]));
    }

    asm volatile("s_nop 7");
    asm volatile("s_nop 7");
    asm volatile("s_nop 7");

    #pragma unroll
    for (int mi = 0; mi < 4; ++mi) {
        #pragma unroll
        for (int ni = 0; ni < 4; ++ni) {
            int col = n0 + wc * 64 + ni * 16 + r;
            #pragma unroll
            for (int j = 0; j < 4; ++j) {
                float v = acc[mi][ni][j];
                if (EPI == 1)      v = (v > 0.f) ? (v + 1.f) : __expf(v);
                else if (EPI == 2) v *= escale;
                else if (EPI == 3) v = (v > 0.f) ? v : 0.f;
                else if (EPI == 4) v = (col < 512) ? ((v > 0.f) ? (v + 1.f) : __expf(v))
                                                   : v * escale;
                int row = m0 + wr * 64 + mi * 16 + g * 4 + j;
                C[(size_t)row * ldc + col] = f2bf(v);
            }
        }
    }
}

// ---------------------------------------------------------------------------
// KV partial over L-chunks: KV[32][32] += K^T v ; Ksum[32] += K. f32 accum.
// K/V read from interleaved qkv with row stride ld. part: [N*H*SPLIT][1056]
// ---------------------------------------------------------------------------
__global__ __launch_bounds__(256)
void kv_partial(const u16* __restrict__ Kf, const u16* __restrict__ Vf, int ld,
                float* __restrict__ part)
{
    int b  = blockIdx.x;
    int s  = b & (KV_SPLIT - 1);
    int nh = b / KV_SPLIT;
    int h  = nh & (N_HEAD - 1);
    int n  = nh / N_HEAD;
    int t  = threadIdx.x;

    __shared__ __align__(16) float Ks[16][D_H];
    __shared__ __align__(16) float Vs[16][D_H];

    const int d   = t >> 3;
    const int dv0 = (t & 7) * 4;
    const int lr  = t >> 4;
    const int lc  = (t & 15) * 2;
    const size_t base = ((size_t)n * L_SEQ) * ld + h * D_H;

    float a0 = 0, a1 = 0, a2 = 0, a3 = 0, asum = 0;
    const int CH = L_SEQ / KV_SPLIT;
    for (int l = s * CH; l < s * CH + CH; l += 16) {
        __syncthreads();
        u32 ku = *(const u32*)&Kf[base + (size_t)(l + lr) * ld + lc];
        u32 vu = *(const u32*)&Vf[base + (size_t)(l + lr) * ld + lc];
        Ks[lr][lc] = bf2f(ku & 0xffff); Ks[lr][lc + 1] = bf2f(ku >> 16);
        Vs[lr][lc] = bf2f(vu & 0xffff); Vs[lr][lc + 1] = bf2f(vu >> 16);
        __syncthreads();
        #pragma unroll
        for (int i = 0; i < 16; ++i) {
            float kv = Ks[i][d];
            float4 vv = *(const float4*)&Vs[i][dv0];
            a0 = fmaf(kv, vv.x, a0);
            a1 = fmaf(kv, vv.y, a1);
            a2 = fmaf(kv, vv.z, a2);
            a3 = fmaf(kv, vv.w, a3);
            asum += kv;
        }
    }
    float* p = part + (size_t)b * 1056;
    p[d * D_H + dv0 + 0] = a0;
    p[d * D_H + dv0 + 1] = a1;
    p[d * D_H + dv0 + 2] = a2;
    p[d * D_H + dv0 + 3] = a3;
    if ((t & 7) == 0) p[1024 + d] = asum;
}

__global__ __launch_bounds__(256)
void kv_final(const float* __restrict__ part, float* __restrict__ KV,
              float* __restrict__ Ksum)
{
    int nh = blockIdx.x;
    int t  = threadIdx.x;
    float ax = 0, ay = 0, az = 0, aw = 0, ssum = 0;
    const float* p0 = part + (size_t)nh * KV_SPLIT * 1056;
    for (int s = 0; s < KV_SPLIT; ++s) {
        const float* p = p0 + (size_t)s * 1056;
        float4 v = *(const float4*)&p[t * 4];
        ax += v.x; ay += v.y; az += v.z; aw += v.w;
        if (t < D_H) ssum += p[1024 + t];
    }
    float4 o = make_float4(ax, ay, az, aw);
    *(float4*)&KV[(size_t)nh * 1024 + t * 4] = o;
    if (t < D_H) Ksum[nh * D_H + t] = ssum;
}

// ---------------------------------------------------------------------------
// attn_msg v2: 32 tokens per block. KV[n] (32KB) + Ksum[n] in LDS once;
// Q staged 8 rows at a time. thread t -> (h=t>>5, dv=t&31).
// msg[tok][t] = (sum_d Q[d]*KV[h][d][dv]) * L / (Q.Ksum_h + eps)
// ---------------------------------------------------------------------------
#define TOK_PER_BLK 32
__global__ __launch_bounds__(256)
void attn_msg2(const u16* __restrict__ Qf, int ldq,
               const float* __restrict__ KV, const float* __restrict__ Ksum,
               u16* __restrict__ msg)
{
    const int t = threadIdx.x;
    const int tok0 = blockIdx.x * TOK_PER_BLK;
    const int n = tok0 / L_SEQ;
    const int h = t >> 5, dv = t & 31;

    __shared__ float KVs[N_HEAD][D_H][D_H];   // 32 KB
    __shared__ float Ss[C_DIM];               // 1 KB
    __shared__ float Qs[8][C_DIM];            // 8 KB

    {
        const float4* src = (const float4*)(KV + (size_t)n * N_HEAD * D_H * D_H);
        float4* dst = (float4*)&KVs[0][0][0];
        #pragma unroll
        for (int i = 0; i < 8; ++i) dst[t + i * 256] = src[t + i * 256];
        Ss[t] = Ksum[n * C_DIM + t];
    }

    const int qt = t >> 5;         // staging row 0..7
    const int qe = (t & 31) * 8;   // staging col

    for (int c = 0; c < TOK_PER_BLK; c += 8) {
        __syncthreads();
        uint4 u = *(const uint4*)(Qf + (size_t)(tok0 + c + qt) * ldq + qe);
        float* qd = &Qs[qt][qe];
        qd[0] = bf2f(u.x & 0xffff); qd[1] = bf2f(u.x >> 16);
        qd[2] = bf2f(u.y & 0xffff); qd[3] = bf2f(u.y >> 16);
        qd[4] = bf2f(u.z & 0xffff); qd[5] = bf2f(u.z >> 16);
        qd[6] = bf2f(u.w & 0xffff); qd[7] = bf2f(u.w >> 16);
        __syncthreads();
        #pragma unroll
        for (int i = 0; i < 8; ++i) {
            const float* qrow = &Qs[i][h * D_H];
            const float* srow = &Ss[h * D_H];
            float zden = 0.f, sacc = 0.f;
            #pragma unroll
            for (int d = 0; d < D_H; ++d) {
                float qv = qrow[d];
                zden = fmaf(qv, srow[d], zden);
                sacc = fmaf(qv, KVs[h][d][dv], sacc);
            }
            float z = (float)L_SEQ / (zden + 1e-6f);
            msg[(size_t)(tok0 + c + i) * C_DIM + t] = f2bf(sacc * z);
        }
    }
}

// ---------------------------------------------------------------------------
// LayerNorm rows of 256, bf16 input. FINAL: out f32 = LN + x residual.
// ---------------------------------------------------------------------------
template<bool FINAL>
__global__ __launch_bounds__(256)
void ln_rows_bf(const u16* __restrict__ X, const float* __restrict__ g,
                const float* __restrict__ b, const float* __restrict__ xres,
                void* __restrict__ Y)
{
    int row  = blockIdx.x * 4 + (threadIdx.x >> 6);
    int lane = threadIdx.x & 63;
    uint2 u = *(const uint2*)(X + (size_t)row * C_DIM + lane * 4);
    float v0 = bf2f(u.x & 0xffff), v1 = bf2f(u.x >> 16);
    float v2 = bf2f(u.y & 0xffff), v3 = bf2f(u.y >> 16);
    float s  = v0 + v1 + v2 + v3;
    float s2 = v0 * v0 + v1 * v1 + v2 * v2 + v3 * v3;
    #pragma unroll
    for (int off = 1; off < 64; off <<= 1) {
        s  += __shfl_xor(s, off);
        s2 += __shfl_xor(s2, off);
    }
    float mu  = s * (1.0f / C_DIM);
    float var = s2 * (1.0f / C_DIM) - mu * mu;
    float rstd = rsqrtf(var + 1e-5f);
    float4 gv = *(const float4*)&g[lane * 4];
    float4 bv = *(const float4*)&b[lane * 4];
    float o0 = (v0 - mu) * rstd * gv.x + bv.x;
    float o1 = (v1 - mu) * rstd * gv.y + bv.y;
    float o2 = (v2 - mu) * rstd * gv.z + bv.z;
    float o3 = (v3 - mu) * rstd * gv.w + bv.w;
    if (FINAL) {
        float4 xv = *(const float4*)&xres[(size_t)row * C_DIM + lane * 4];
        float4 o = make_float4(o0 + xv.x, o1 + xv.y, o2 + xv.z, o3 + xv.w);
        *(float4*)((float*)Y + (size_t)row * C_DIM + lane * 4) = o;
    } else {
        uint2 o;
        o.x = (u32)f2bf(o0) | ((u32)f2bf(o1) << 16);
        o.y = (u32)f2bf(o2) | ((u32)f2bf(o3) << 16);
        *(uint2*)((u16*)Y + (size_t)row * C_DIM + lane * 4) = o;
    }
}

// ---------------------------------------------------------------------------
extern "C" void kernel_launch(void* const* d_in, const int* in_sizes, int n_in,
                              void* d_out, int out_size, void* d_ws, size_t ws_size,
                              hipStream_t stream)
{
    const float* x  = (const float*)d_in[0];
    const float* Wq = (const float*)d_in[1];
    const float* Wk = (const float*)d_in[2];
    const float* Wv = (const float*)d_in[3];
    const float* Wm = (const float*)d_in[4];
    const float* W1 = (const float*)d_in[5];
    const float* W2 = (const float*)d_in[6];
    const float* g1 = (const float*)d_in[7];
    const float* b1 = (const float*)d_in[8];
    const float* g2 = (const float*)d_in[9];
    const float* b2 = (const float*)d_in[10];
    float* out = (float*)d_out;

    const size_t SLAB = (size_t)M_ROWS * C_DIM;   // 16,777,216 elems
    u16* xb   = (u16*)d_ws;                // 1 slab
    u16* qkv  = xb + SLAB;                 // 3 slabs, ld = 768
    u16* msg  = qkv + 3 * SLAB;            // 1 slab
    // liveness reuse inside dead qkv:
    u16* m1   = qkv;                       // after attn_msg
    u16* ln1  = qkv + 2 * SLAB;            // after ln1 write; live through W1
    u16* h    = qkv;                       // 2 slabs (m1 dead), avoids ln1
    u16* mlp  = msg;                       // msg dead after Wm gemm
    // weights (transposed bf16)
    u16* wqkvt = msg + SLAB;               // 768*256
    u16* wmt   = wqkvt + 768 * 256;
    u16* w1t   = wmt + 256 * 256;          // 512*512
    u16* w2t   = w1t + 512 * 512;          // 256*512
    float* KV   = (float*)(w2t + 256 * 512);
    float* Ksum = KV + (size_t)N_BATCH * N_HEAD * D_H * D_H;
    float* part = Ksum + (size_t)N_BATCH * N_HEAD * D_H;

    dim3 blk(256);
    const float invL = 1.0f / (float)L_SEQ;

    // ---- prep ----
    f32_to_bf16_k<<<2048, blk, 0, stream>>>(x, xb, (int)(SLAB / 8));
    w_prep<<<640, blk, 0, stream>>>(Wq, Wk, Wv, Wm, W1, W2, wqkvt, wmt, w1t, w2t);

    // ---- fused QKV projection: qkv[M][768] ----
    gemm_bf16<4><<<dim3(6, M_ROWS / 128), blk, 0, stream>>>(
        xb, xb, 256, 256, 256, wqkvt, 256, qkv, 768, 256, invL);

    // ---- KV reduction ----
    kv_partial<<<N_BATCH * N_HEAD * KV_SPLIT, blk, 0, stream>>>(
        qkv + 256, qkv + 512, 768, part);
    kv_final<<<N_BATCH * N_HEAD, blk, 0, stream>>>(part, KV, Ksum);

    // ---- attention message ----
    attn_msg2<<<M_ROWS / TOK_PER_BLK, blk, 0, stream>>>(qkv, 768, KV, Ksum, msg);

    // ---- merge heads + LN1 ----
    gemm_bf16<0><<<dim3(2, M_ROWS / 128), blk, 0, stream>>>(
        msg, msg, 256, 256, 256, wmt, 256, m1, 256, 256, 1.f);
    ln_rows_bf<false><<<M_ROWS / 4, blk, 0, stream>>>(m1, g1, b1, nullptr, (void*)ln1);

    // ---- MLP ----
    gemm_bf16<3><<<dim3(4, M_ROWS / 128), blk, 0, stream>>>(
        xb, ln1, 256, 256, 256, w1t, 512, h, 512, 512, 1.f);
    gemm_bf16<0><<<dim3(2, M_ROWS / 128), blk, 0, stream>>>(
        h, h, 512, 512, 512, w2t, 512, mlp, 256, 512, 1.f);

    // ---- LN2 + residual ----
    ln_rows_bf<true><<<M_ROWS / 4, blk, 0, stream>>>(mlp, g2, b2, x, out);
}

// Round 4
// 306.907 us; speedup vs baseline: 1.1667x; 1.1667x over previous
//
#include <hip/hip_runtime.h>
#include <hip/hip_bf16.h>
#include <math.h>

#define L_SEQ   16384
#define C_DIM   256
#define N_BATCH 4
#define N_HEAD  8
#define D_H     32
#define M_ROWS  (N_BATCH * L_SEQ)   // 65536
#define KV_SPLIT 64

typedef unsigned short u16;
typedef unsigned int   u32;
typedef short s16x8 __attribute__((ext_vector_type(8)));
typedef float f32x4 __attribute__((ext_vector_type(4)));

// ---- bf16 helpers (bit-exact bf16->f32; RNE f32->bf16) ----------------------
__device__ __forceinline__ float bf2f(u32 lo16) { return __uint_as_float(lo16 << 16); }
__device__ __forceinline__ u16 f2bf(float f) {
    u32 u = __float_as_uint(f);
    u32 rb = ((u >> 16) & 1u) + 0x7fffu;
    return (u16)((u + rb) >> 16);
}

// ---- async global->LDS, 16B per lane ---------------------------------------
__device__ __forceinline__ void gl_lds16(const u16* g, u16* l) {
    __builtin_amdgcn_global_load_lds(
        (__attribute__((address_space(1))) void*)g,
        (__attribute__((address_space(3))) void*)l, 16, 0, 0);
}

// ---------------------------------------------------------------------------
// f32 -> bf16 bulk convert (8 elems/thread/iter)
// ---------------------------------------------------------------------------
__global__ __launch_bounds__(256)
void f32_to_bf16_k(const float* __restrict__ in, u16* __restrict__ out, int n8)
{
    int i = blockIdx.x * blockDim.x + threadIdx.x;
    int stride = gridDim.x * blockDim.x;
    for (; i < n8; i += stride) {
        float4 f0 = ((const float4*)in)[(size_t)i * 2];
        float4 f1 = ((const float4*)in)[(size_t)i * 2 + 1];
        uint4 o;
        o.x = (u32)f2bf(f0.x) | ((u32)f2bf(f0.y) << 16);
        o.y = (u32)f2bf(f0.z) | ((u32)f2bf(f0.w) << 16);
        o.z = (u32)f2bf(f1.x) | ((u32)f2bf(f1.y) << 16);
        o.w = (u32)f2bf(f1.z) | ((u32)f2bf(f1.w) << 16);
        ((uint4*)out)[i] = o;
    }
}

// ---------------------------------------------------------------------------
// All weight transposes in one kernel. W[K][N] f32 -> Wt[rowoff+n][K] bf16.
// ---------------------------------------------------------------------------
__global__ __launch_bounds__(256)
void w_prep(const float* __restrict__ Wq, const float* __restrict__ Wk,
            const float* __restrict__ Wv, const float* __restrict__ Wm,
            const float* __restrict__ W1, const float* __restrict__ W2,
            u16* __restrict__ wqkvt, u16* __restrict__ wmt,
            u16* __restrict__ w1t, u16* __restrict__ w2t)
{
    __shared__ float tile[32][33];
    int bt = blockIdx.x;
    const float* src; u16* dst; int K, N, rowoff, tt;
    if (bt < 192)      { int w = bt >> 6; tt = bt & 63;
                         src = (w == 0) ? Wq : (w == 1) ? Wk : Wv;
                         dst = wqkvt; K = 256; N = 256; rowoff = w * 256; }
    else if (bt < 256) { tt = bt - 192; src = Wm; dst = wmt; K = 256; N = 256; rowoff = 0; }
    else if (bt < 512) { tt = bt - 256; src = W1; dst = w1t; K = 512; N = 512; rowoff = 0; }
    else               { tt = bt - 512; src = W2; dst = w2t; K = 512; N = 256; rowoff = 0; }
    int ntx = N >> 5;
    int n0 = (tt % ntx) * 32, k0 = (tt / ntx) * 32;
    int tx = threadIdx.x & 31, ty = threadIdx.x >> 5;
    #pragma unroll
    for (int i = 0; i < 32; i += 8)
        tile[ty + i][tx] = src[(size_t)(k0 + ty + i) * N + n0 + tx];
    __syncthreads();
    #pragma unroll
    for (int i = 0; i < 32; i += 8)
        dst[(size_t)(rowoff + n0 + ty + i) * K + k0 + tx] = f2bf(tile[tx][ty + i]);
}

// ---------------------------------------------------------------------------
// bf16 MFMA GEMM: C[., ldc] = EPI( concat(A1,A2)[M,K] @ Bt^T )
// Bt[N][K] bf16 (transposed). Tile 128x128, BK=32, 4 waves, 4x4 16x16x32 MFMA.
// bstride: per-batch B advance (elements) -- Bt += (m0/L_SEQ)*bstride.
// EPI: 0=none, 1=elu+1, 2=x*escale, 3=relu, 4=qkv(col<512:elu+1 else *escale)
// ---------------------------------------------------------------------------
template<int EPI>
__global__ __launch_bounds__(256)
void gemm_bf16(const u16* __restrict__ A1, const u16* __restrict__ A2,
               int KA, int sA1, int sA2,
               const u16* __restrict__ Bt, int ldb, int bstride,
               u16* __restrict__ C, int ldc, int K, float escale)
{
    __shared__ __align__(16) u16 As[128 * 32];
    __shared__ __align__(16) u16 Bs[128 * 32];

    const int tid = threadIdx.x;
    const int m0 = blockIdx.y * 128;
    const int n0 = blockIdx.x * 128;
    const int w = tid >> 6, lane = tid & 63;
    const int wr = w >> 1, wc = w & 1;
    const int g = lane >> 4, r = lane & 15;

    Bt += (size_t)(m0 / L_SEQ) * bstride;

    f32x4 acc[4][4] = {};

    const int ktiles = K / 32;
    for (int kt = 0; kt < ktiles; ++kt) {
        __syncthreads();
        #pragma unroll
        for (int i = 0; i < 2; ++i) {
            int li  = i * 256 + tid;
            int row = li >> 2, kc = li & 3;
            int kg = kt * 32 + kc * 8;
            const u16* Ap = (kg < KA) ? A1 : A2;
            int stride    = (kg < KA) ? sA1 : sA2;
            int col       = (kg < KA) ? kg  : kg - KA;
            gl_lds16(Ap + (size_t)(m0 + row) * stride + col, &As[li * 8]);
            gl_lds16(Bt + (size_t)(n0 + row) * ldb + kt * 32 + kc * 8, &Bs[li * 8]);
        }
        __syncthreads();

        s16x8 a[4], b[4];
        #pragma unroll
        for (int mi = 0; mi < 4; ++mi)
            a[mi] = *(const s16x8*)&As[(wr * 64 + mi * 16 + r) * 32 + g * 8];
        #pragma unroll
        for (int ni = 0; ni < 4; ++ni)
            b[ni] = *(const s16x8*)&Bs[(wc * 64 + ni * 16 + r) * 32 + g * 8];
        #pragma unroll
        for (int mi = 0; mi < 4; ++mi)
            #pragma unroll
            for (int ni = 0; ni < 4; ++ni)
                asm volatile("v_mfma_f32_16x16x32_bf16 %0, %1, %2, %0"
                             : "+v"(acc[mi][ni]) : "v"(a[mi]), "v"(b[ni]));
    }

    asm volatile("s_nop 7");
    asm volatile("s_nop 7");
    asm volatile("s_nop 7");

    #pragma unroll
    for (int mi = 0; mi < 4; ++mi) {
        #pragma unroll
        for (int ni = 0; ni < 4; ++ni) {
            int col = n0 + wc * 64 + ni * 16 + r;
            #pragma unroll
            for (int j = 0; j < 4; ++j) {
                float v = acc[mi][ni][j];
                if (EPI == 1)      v = (v > 0.f) ? (v + 1.f) : __expf(v);
                else if (EPI == 2) v *= escale;
                else if (EPI == 3) v = (v > 0.f) ? v : 0.f;
                else if (EPI == 4) v = (col < 512) ? ((v > 0.f) ? (v + 1.f) : __expf(v))
                                                   : v * escale;
                int row = m0 + wr * 64 + mi * 16 + g * 4 + j;
                C[(size_t)row * ldc + col] = f2bf(v);
            }
        }
    }
}

// ---------------------------------------------------------------------------
// KV partial over L-chunks: KV[32][32] += K^T v ; Ksum[32] += K. f32 accum.
// ---------------------------------------------------------------------------
__global__ __launch_bounds__(256)
void kv_partial(const u16* __restrict__ Kf, const u16* __restrict__ Vf, int ld,
                float* __restrict__ part)
{
    int b  = blockIdx.x;
    int s  = b & (KV_SPLIT - 1);
    int nh = b / KV_SPLIT;
    int h  = nh & (N_HEAD - 1);
    int n  = nh / N_HEAD;
    int t  = threadIdx.x;

    __shared__ __align__(16) float Ks[16][D_H];
    __shared__ __align__(16) float Vs[16][D_H];

    const int d   = t >> 3;
    const int dv0 = (t & 7) * 4;
    const int lr  = t >> 4;
    const int lc  = (t & 15) * 2;
    const size_t base = ((size_t)n * L_SEQ) * ld + h * D_H;

    float a0 = 0, a1 = 0, a2 = 0, a3 = 0, asum = 0;
    const int CH = L_SEQ / KV_SPLIT;
    for (int l = s * CH; l < s * CH + CH; l += 16) {
        __syncthreads();
        u32 ku = *(const u32*)&Kf[base + (size_t)(l + lr) * ld + lc];
        u32 vu = *(const u32*)&Vf[base + (size_t)(l + lr) * ld + lc];
        Ks[lr][lc] = bf2f(ku & 0xffff); Ks[lr][lc + 1] = bf2f(ku >> 16);
        Vs[lr][lc] = bf2f(vu & 0xffff); Vs[lr][lc + 1] = bf2f(vu >> 16);
        __syncthreads();
        #pragma unroll
        for (int i = 0; i < 16; ++i) {
            float kv = Ks[i][d];
            float4 vv = *(const float4*)&Vs[i][dv0];
            a0 = fmaf(kv, vv.x, a0);
            a1 = fmaf(kv, vv.y, a1);
            a2 = fmaf(kv, vv.z, a2);
            a3 = fmaf(kv, vv.w, a3);
            asum += kv;
        }
    }
    float* p = part + (size_t)b * 1056;
    p[d * D_H + dv0 + 0] = a0;
    p[d * D_H + dv0 + 1] = a1;
    p[d * D_H + dv0 + 2] = a2;
    p[d * D_H + dv0 + 3] = a3;
    if ((t & 7) == 0) p[1024 + d] = asum;
}

__global__ __launch_bounds__(256)
void kv_final(const float* __restrict__ part, float* __restrict__ KV,
              float* __restrict__ Ksum)
{
    int nh = blockIdx.x;
    int t  = threadIdx.x;
    float ax = 0, ay = 0, az = 0, aw = 0, ssum = 0;
    const float* p0 = part + (size_t)nh * KV_SPLIT * 1056;
    for (int s = 0; s < KV_SPLIT; ++s) {
        const float* p = p0 + (size_t)s * 1056;
        float4 v = *(const float4*)&p[t * 4];
        ax += v.x; ay += v.y; az += v.z; aw += v.w;
        if (t < D_H) ssum += p[1024 + t];
    }
    float4 o = make_float4(ax, ay, az, aw);
    *(float4*)&KV[(size_t)nh * 1024 + t * 4] = o;
    if (t < D_H) Ksum[nh * D_H + t] = ssum;
}

// ---------------------------------------------------------------------------
// Build block-diagonal B for the attention GEMM:
// bd[b][n][k] = (k>>5==n>>5) ? KV[b][n>>5][k&31][n&31] : 0   (bf16, Bt layout)
// ---------------------------------------------------------------------------
__global__ __launch_bounds__(256)
void bd_build(const float* __restrict__ KV, u16* __restrict__ bd)
{
    int idx = blockIdx.x * 256 + threadIdx.x;      // 0 .. 4*256*256-1
    int b = idx >> 16;
    int n = (idx >> 8) & 255;
    int k = idx & 255;
    int h = n >> 5, dv = n & 31;
    float v = ((k >> 5) == h) ? KV[(((size_t)b * N_HEAD + h) * D_H + (k & 31)) * D_H + dv] : 0.f;
    bd[idx] = f2bf(v);
}

// ---------------------------------------------------------------------------
// attn_norm: msg[tok][c] *= L / (Q[tok] . Ksum_head(c) + eps), in place.
// One wave per token, lane covers 4 cols; per-head reduce via shfl_xor(1,2,4).
// ---------------------------------------------------------------------------
#define NT_TOK 32
__global__ __launch_bounds__(256)
void attn_norm(const u16* __restrict__ q, int ldq,
               const float* __restrict__ Ksum, u16* __restrict__ msg)
{
    const int t = threadIdx.x;
    const int w = t >> 6, lane = t & 63;
    const int tok0 = blockIdx.x * NT_TOK;
    const int n = tok0 / L_SEQ;
    float4 ks = *(const float4*)&Ksum[n * C_DIM + lane * 4];

    for (int i = 0; i < NT_TOK; i += 4) {
        int tok = tok0 + i + w;
        uint2 qu = *(const uint2*)(q + (size_t)tok * ldq + lane * 4);
        float p = bf2f(qu.x & 0xffff) * ks.x + bf2f(qu.x >> 16) * ks.y
                + bf2f(qu.y & 0xffff) * ks.z + bf2f(qu.y >> 16) * ks.w;
        p += __shfl_xor(p, 1);
        p += __shfl_xor(p, 2);
        p += __shfl_xor(p, 4);
        float z = (float)L_SEQ / (p + 1e-6f);
        u16* mp = msg + (size_t)tok * C_DIM + lane * 4;
        uint2 mu = *(const uint2*)mp;
        uint2 o;
        o.x = (u32)f2bf(bf2f(mu.x & 0xffff) * z) | ((u32)f2bf(bf2f(mu.x >> 16) * z) << 16);
        o.y = (u32)f2bf(bf2f(mu.y & 0xffff) * z) | ((u32)f2bf(bf2f(mu.y >> 16) * z) << 16);
        *(uint2*)mp = o;
    }
}

// ---------------------------------------------------------------------------
// LayerNorm rows of 256, bf16 input. FINAL: out f32 = LN + x residual.
// ---------------------------------------------------------------------------
template<bool FINAL>
__global__ __launch_bounds__(256)
void ln_rows_bf(const u16* __restrict__ X, const float* __restrict__ g,
                const float* __restrict__ b, const float* __restrict__ xres,
                void* __restrict__ Y)
{
    int row  = blockIdx.x * 4 + (threadIdx.x >> 6);
    int lane = threadIdx.x & 63;
    uint2 u = *(const uint2*)(X + (size_t)row * C_DIM + lane * 4);
    float v0 = bf2f(u.x & 0xffff), v1 = bf2f(u.x >> 16);
    float v2 = bf2f(u.y & 0xffff), v3 = bf2f(u.y >> 16);
    float s  = v0 + v1 + v2 + v3;
    float s2 = v0 * v0 + v1 * v1 + v2 * v2 + v3 * v3;
    #pragma unroll
    for (int off = 1; off < 64; off <<= 1) {
        s  += __shfl_xor(s, off);
        s2 += __shfl_xor(s2, off);
    }
    float mu  = s * (1.0f / C_DIM);
    float var = s2 * (1.0f / C_DIM) - mu * mu;
    float rstd = rsqrtf(var + 1e-5f);
    float4 gv = *(const float4*)&g[lane * 4];
    float4 bv = *(const float4*)&b[lane * 4];
    float o0 = (v0 - mu) * rstd * gv.x + bv.x;
    float o1 = (v1 - mu) * rstd * gv.y + bv.y;
    float o2 = (v2 - mu) * rstd * gv.z + bv.z;
    float o3 = (v3 - mu) * rstd * gv.w + bv.w;
    if (FINAL) {
        float4 xv = *(const float4*)&xres[(size_t)row * C_DIM + lane * 4];
        float4 o = make_float4(o0 + xv.x, o1 + xv.y, o2 + xv.z, o3 + xv.w);
        *(float4*)((float*)Y + (size_t)row * C_DIM + lane * 4) = o;
    } else {
        uint2 o;
        o.x = (u32)f2bf(o0) | ((u32)f2bf(o1) << 16);
        o.y = (u32)f2bf(o2) | ((u32)f2bf(o3) << 16);
        *(uint2*)((u16*)Y + (size_t)row * C_DIM + lane * 4) = o;
    }
}

// ---------------------------------------------------------------------------
extern "C" void kernel_launch(void* const* d_in, const int* in_sizes, int n_in,
                              void* d_out, int out_size, void* d_ws, size_t ws_size,
                              hipStream_t stream)
{
    const float* x  = (const float*)d_in[0];
    const float* Wq = (const float*)d_in[1];
    const float* Wk = (const float*)d_in[2];
    const float* Wv = (const float*)d_in[3];
    const float* Wm = (const float*)d_in[4];
    const float* W1 = (const float*)d_in[5];
    const float* W2 = (const float*)d_in[6];
    const float* g1 = (const float*)d_in[7];
    const float* b1 = (const float*)d_in[8];
    const float* g2 = (const float*)d_in[9];
    const float* b2 = (const float*)d_in[10];
    float* out = (float*)d_out;

    const size_t SLAB = (size_t)M_ROWS * C_DIM;   // 16,777,216 elems
    u16* xb   = (u16*)d_ws;                // 1 slab
    u16* qkv  = xb + SLAB;                 // 3 slabs, ld = 768
    u16* msg  = qkv + 3 * SLAB;            // 1 slab
    // liveness reuse inside dead qkv:
    u16* m1   = qkv;                       // after attn_norm
    u16* ln1  = qkv + 2 * SLAB;            // live through W1
    u16* h    = qkv;                       // 2 slabs (m1 dead)
    u16* mlp  = msg;                       // msg dead after Wm gemm
    // weights (transposed bf16)
    u16* wqkvt = msg + SLAB;               // 768*256
    u16* wmt   = wqkvt + 768 * 256;
    u16* w1t   = wmt + 256 * 256;          // 512*512
    u16* w2t   = w1t + 512 * 512;          // 256*512
    u16* bd    = w2t + 256 * 512;          // 4*256*256 bf16 block-diag KV
    float* KV   = (float*)(bd + (size_t)N_BATCH * 256 * 256);
    float* Ksum = KV + (size_t)N_BATCH * N_HEAD * D_H * D_H;
    float* part = Ksum + (size_t)N_BATCH * N_HEAD * D_H;

    dim3 blk(256);
    const float invL = 1.0f / (float)L_SEQ;

    // ---- prep ----
    f32_to_bf16_k<<<2048, blk, 0, stream>>>(x, xb, (int)(SLAB / 8));
    w_prep<<<640, blk, 0, stream>>>(Wq, Wk, Wv, Wm, W1, W2, wqkvt, wmt, w1t, w2t);

    // ---- fused QKV projection: qkv[M][768] ----
    gemm_bf16<4><<<dim3(6, M_ROWS / 128), blk, 0, stream>>>(
        xb, xb, 256, 256, 256, wqkvt, 256, 0, qkv, 768, 256, invL);

    // ---- KV reduction ----
    kv_partial<<<N_BATCH * N_HEAD * KV_SPLIT, blk, 0, stream>>>(
        qkv + 256, qkv + 512, 768, part);
    kv_final<<<N_BATCH * N_HEAD, blk, 0, stream>>>(part, KV, Ksum);

    // ---- attention message: msg_raw = Q @ BD(KV), then normalize ----
    bd_build<<<(N_BATCH * 256 * 256) / 256, blk, 0, stream>>>(KV, bd);
    gemm_bf16<0><<<dim3(2, M_ROWS / 128), blk, 0, stream>>>(
        qkv, qkv, 256, 768, 768, bd, 256, 256 * 256, msg, 256, 256, 1.f);
    attn_norm<<<M_ROWS / NT_TOK, blk, 0, stream>>>(qkv, 768, Ksum, msg);

    // ---- merge heads + LN1 ----
    gemm_bf16<0><<<dim3(2, M_ROWS / 128), blk, 0, stream>>>(
        msg, msg, 256, 256, 256, wmt, 256, 0, m1, 256, 256, 1.f);
    ln_rows_bf<false><<<M_ROWS / 4, blk, 0, stream>>>(m1, g1, b1, nullptr, (void*)ln1);

    // ---- MLP ----
    gemm_bf16<3><<<dim3(4, M_ROWS / 128), blk, 0, stream>>>(
        xb, ln1, 256, 256, 256, w1t, 512, 0, h, 512, 512, 1.f);
    gemm_bf16<0><<<dim3(2, M_ROWS / 128), blk, 0, stream>>>(
        h, h, 512, 512, 512, w2t, 512, 0, mlp, 256, 512, 1.f);

    // ---- LN2 + residual ----
    ln_rows_bf<true><<<M_ROWS / 4, blk, 0, stream>>>(mlp, g2, b2, x, out);
}

// Round 5
// 287.492 us; speedup vs baseline: 1.2455x; 1.0675x over previous
//
#include <hip/hip_runtime.h>
#include <hip/hip_bf16.h>
#include <math.h>

#define L_SEQ   16384
#define C_DIM   256
#define N_BATCH 4
#define N_HEAD  8
#define D_H     32
#define M_ROWS  (N_BATCH * L_SEQ)   // 65536
#define KV_SPLIT 64
#define SLAB_E  ((size_t)M_ROWS * C_DIM)   // 16,777,216 elems

typedef unsigned short u16;
typedef unsigned int   u32;
typedef short s16x8 __attribute__((ext_vector_type(8)));
typedef float f32x4 __attribute__((ext_vector_type(4)));

// ---- bf16 helpers (bit-exact bf16->f32; RNE f32->bf16) ----------------------
__device__ __forceinline__ float bf2f(u32 lo16) { return __uint_as_float(lo16 << 16); }
__device__ __forceinline__ u16 f2bf(float f) {
    u32 u = __float_as_uint(f);
    u32 rb = ((u >> 16) & 1u) + 0x7fffu;
    return (u16)((u + rb) >> 16);
}

// ---- async global->LDS, 16B per lane ---------------------------------------
__device__ __forceinline__ void gl_lds16(const u16* g, u16* l) {
    __builtin_amdgcn_global_load_lds(
        (__attribute__((address_space(1))) void*)g,
        (__attribute__((address_space(3))) void*)l, 16, 0, 0);
}

// ---------------------------------------------------------------------------
// f32 -> bf16 bulk convert (8 elems/thread/iter)
// ---------------------------------------------------------------------------
__global__ __launch_bounds__(256)
void f32_to_bf16_k(const float* __restrict__ in, u16* __restrict__ out, int n8)
{
    int i = blockIdx.x * blockDim.x + threadIdx.x;
    int stride = gridDim.x * blockDim.x;
    for (; i < n8; i += stride) {
        float4 f0 = ((const float4*)in)[(size_t)i * 2];
        float4 f1 = ((const float4*)in)[(size_t)i * 2 + 1];
        uint4 o;
        o.x = (u32)f2bf(f0.x) | ((u32)f2bf(f0.y) << 16);
        o.y = (u32)f2bf(f0.z) | ((u32)f2bf(f0.w) << 16);
        o.z = (u32)f2bf(f1.x) | ((u32)f2bf(f1.y) << 16);
        o.w = (u32)f2bf(f1.z) | ((u32)f2bf(f1.w) << 16);
        ((uint4*)out)[i] = o;
    }
}

// ---------------------------------------------------------------------------
// All weight transposes in one kernel. W[K][N] f32 -> Wt[rowoff+n][K] bf16.
// ---------------------------------------------------------------------------
__global__ __launch_bounds__(256)
void w_prep(const float* __restrict__ Wq, const float* __restrict__ Wk,
            const float* __restrict__ Wv, const float* __restrict__ Wm,
            const float* __restrict__ W1, const float* __restrict__ W2,
            u16* __restrict__ wqkvt, u16* __restrict__ wmt,
            u16* __restrict__ w1t, u16* __restrict__ w2t)
{
    __shared__ float tile[32][33];
    int bt = blockIdx.x;
    const float* src; u16* dst; int K, N, rowoff, tt;
    if (bt < 192)      { int w = bt >> 6; tt = bt & 63;
                         src = (w == 0) ? Wq : (w == 1) ? Wk : Wv;
                         dst = wqkvt; K = 256; N = 256; rowoff = w * 256; }
    else if (bt < 256) { tt = bt - 192; src = Wm; dst = wmt; K = 256; N = 256; rowoff = 0; }
    else if (bt < 512) { tt = bt - 256; src = W1; dst = w1t; K = 512; N = 512; rowoff = 0; }
    else               { tt = bt - 512; src = W2; dst = w2t; K = 512; N = 256; rowoff = 0; }
    int ntx = N >> 5;
    int n0 = (tt % ntx) * 32, k0 = (tt / ntx) * 32;
    int tx = threadIdx.x & 31, ty = threadIdx.x >> 5;
    #pragma unroll
    for (int i = 0; i < 32; i += 8)
        tile[ty + i][tx] = src[(size_t)(k0 + ty + i) * N + n0 + tx];
    __syncthreads();
    #pragma unroll
    for (int i = 0; i < 32; i += 8)
        dst[(size_t)(rowoff + n0 + ty + i) * K + k0 + tx] = f2bf(tile[tx][ty + i]);
}

// ---------------------------------------------------------------------------
// bf16 MFMA GEMM, 2-phase double-buffered staging, C^T fragments (vectorized
// 8B stores), XCD-chunked block swizzle (1D grid, nwg%8==0).
// C = EPI( concat(A1,A2)[M,K] @ Bt^T ),  Bt[N][K] bf16.
// Tile 128x128, BK=32, 4 waves, 4x4 of 16x16x32 MFMA.
// bstride: per-batch B advance. EPI: 0=none, 3=relu,
//   4=qkv: col<512 -> elu+1 (q,k slabs), col>=512 -> *escale (v slab);
//          C is q-slab base; k = C+SLAB_E, v = C+2*SLAB_E, ldc=256.
// ---------------------------------------------------------------------------
template<int EPI>
__global__ __launch_bounds__(256)
void gemm_bf16(const u16* __restrict__ A1, const u16* __restrict__ A2,
               int KA, int sA1, int sA2,
               const u16* __restrict__ Bt, int ldb, int bstride,
               u16* __restrict__ C, int ldc, int K, float escale, int nx)
{
    __shared__ __align__(16) u16 As[2][128 * 32];
    __shared__ __align__(16) u16 Bs[2][128 * 32];

    const int tid = threadIdx.x;
    // XCD-chunked swizzle: consecutive logical blocks (same A-rows) on same XCD
    const int nwg = gridDim.x;
    const int cpx = nwg >> 3;
    const int hb  = blockIdx.x;
    const int lb  = (hb & 7) * cpx + (hb >> 3);
    const int m0 = (lb / nx) * 128;
    const int n0 = (lb % nx) * 128;
    const int w = tid >> 6, lane = tid & 63;
    const int wr = w >> 1, wc = w & 1;
    const int g = lane >> 4, r = lane & 15;

    Bt += (size_t)(m0 / L_SEQ) * bstride;

    f32x4 acc[4][4] = {};

    auto stage = [&](int buf, int kt) {
        #pragma unroll
        for (int i = 0; i < 2; ++i) {
            int li  = i * 256 + tid;
            int row = li >> 2, kc = li & 3;
            int kg = kt * 32 + kc * 8;
            const u16* Ap = (kg < KA) ? A1 : A2;
            int stride    = (kg < KA) ? sA1 : sA2;
            int col       = (kg < KA) ? kg  : kg - KA;
            gl_lds16(Ap + (size_t)(m0 + row) * stride + col, &As[buf][li * 8]);
            gl_lds16(Bt + (size_t)(n0 + row) * ldb + kt * 32 + kc * 8, &Bs[buf][li * 8]);
        }
    };

    const int ktiles = K / 32;
    stage(0, 0);
    __syncthreads();
    int cur = 0;
    for (int kt = 0; kt < ktiles; ++kt) {
        if (kt + 1 < ktiles) stage(cur ^ 1, kt + 1);  // prefetch overlaps compute

        s16x8 a[4], b[4];
        #pragma unroll
        for (int mi = 0; mi < 4; ++mi)
            a[mi] = *(const s16x8*)&As[cur][(wr * 64 + mi * 16 + r) * 32 + g * 8];
        #pragma unroll
        for (int ni = 0; ni < 4; ++ni)
            b[ni] = *(const s16x8*)&Bs[cur][(wc * 64 + ni * 16 + r) * 32 + g * 8];
        // swapped operands -> C^T frags: reg j = col ni*16+g*4+j at row mi*16+r
        #pragma unroll
        for (int mi = 0; mi < 4; ++mi)
            #pragma unroll
            for (int ni = 0; ni < 4; ++ni)
                asm volatile("v_mfma_f32_16x16x32_bf16 %0, %1, %2, %0"
                             : "+v"(acc[mi][ni]) : "v"(b[ni]), "v"(a[mi]));

        __syncthreads();   // drains prefetch (vmcnt) + LDS reads
        cur ^= 1;
    }

    asm volatile("s_nop 7");
    asm volatile("s_nop 7");
    asm volatile("s_nop 7");

    #pragma unroll
    for (int mi = 0; mi < 4; ++mi) {
        int row = m0 + wr * 64 + mi * 16 + r;
        #pragma unroll
        for (int ni = 0; ni < 4; ++ni) {
            int col0 = n0 + wc * 64 + ni * 16 + g * 4;
            ushort4 o;
            #pragma unroll
            for (int j = 0; j < 4; ++j) {
                float v = acc[mi][ni][j];
                if (EPI == 3)      v = (v > 0.f) ? v : 0.f;
                else if (EPI == 4) v = (col0 < 512) ? ((v > 0.f) ? (v + 1.f) : __expf(v))
                                                    : v * escale;
                (&o.x)[j] = f2bf(v);
            }
            if (EPI == 4) {
                u16* dst = (col0 < 256) ? C + (size_t)row * 256 + col0
                         : (col0 < 512) ? C + SLAB_E + (size_t)row * 256 + (col0 - 256)
                                        : C + 2 * SLAB_E + (size_t)row * 256 + (col0 - 512);
                *(ushort4*)dst = o;
            } else {
                *(ushort4*)&C[(size_t)row * ldc + col0] = o;
            }
        }
    }
}

// ---------------------------------------------------------------------------
// KV partial over L-chunks: KV[32][32] += K^T v ; Ksum[32] += K. f32 accum.
// ---------------------------------------------------------------------------
__global__ __launch_bounds__(256)
void kv_partial(const u16* __restrict__ Kf, const u16* __restrict__ Vf, int ld,
                float* __restrict__ part)
{
    int b  = blockIdx.x;
    int s  = b & (KV_SPLIT - 1);
    int nh = b / KV_SPLIT;
    int h  = nh & (N_HEAD - 1);
    int n  = nh / N_HEAD;
    int t  = threadIdx.x;

    __shared__ __align__(16) float Ks[16][D_H];
    __shared__ __align__(16) float Vs[16][D_H];

    const int d   = t >> 3;
    const int dv0 = (t & 7) * 4;
    const int lr  = t >> 4;
    const int lc  = (t & 15) * 2;
    const size_t base = ((size_t)n * L_SEQ) * ld + h * D_H;

    float a0 = 0, a1 = 0, a2 = 0, a3 = 0, asum = 0;
    const int CH = L_SEQ / KV_SPLIT;
    for (int l = s * CH; l < s * CH + CH; l += 16) {
        __syncthreads();
        u32 ku = *(const u32*)&Kf[base + (size_t)(l + lr) * ld + lc];
        u32 vu = *(const u32*)&Vf[base + (size_t)(l + lr) * ld + lc];
        Ks[lr][lc] = bf2f(ku & 0xffff); Ks[lr][lc + 1] = bf2f(ku >> 16);
        Vs[lr][lc] = bf2f(vu & 0xffff); Vs[lr][lc + 1] = bf2f(vu >> 16);
        __syncthreads();
        #pragma unroll
        for (int i = 0; i < 16; ++i) {
            float kv = Ks[i][d];
            float4 vv = *(const float4*)&Vs[i][dv0];
            a0 = fmaf(kv, vv.x, a0);
            a1 = fmaf(kv, vv.y, a1);
            a2 = fmaf(kv, vv.z, a2);
            a3 = fmaf(kv, vv.w, a3);
            asum += kv;
        }
    }
    float* p = part + (size_t)b * 1056;
    p[d * D_H + dv0 + 0] = a0;
    p[d * D_H + dv0 + 1] = a1;
    p[d * D_H + dv0 + 2] = a2;
    p[d * D_H + dv0 + 3] = a3;
    if ((t & 7) == 0) p[1024 + d] = asum;
}

__global__ __launch_bounds__(256)
void kv_final(const float* __restrict__ part, float* __restrict__ KV,
              float* __restrict__ Ksum)
{
    int nh = blockIdx.x;
    int t  = threadIdx.x;
    float ax = 0, ay = 0, az = 0, aw = 0, ssum = 0;
    const float* p0 = part + (size_t)nh * KV_SPLIT * 1056;
    for (int s = 0; s < KV_SPLIT; ++s) {
        const float* p = p0 + (size_t)s * 1056;
        float4 v = *(const float4*)&p[t * 4];
        ax += v.x; ay += v.y; az += v.z; aw += v.w;
        if (t < D_H) ssum += p[1024 + t];
    }
    float4 o = make_float4(ax, ay, az, aw);
    *(float4*)&KV[(size_t)nh * 1024 + t * 4] = o;
    if (t < D_H) Ksum[nh * D_H + t] = ssum;
}

// ---------------------------------------------------------------------------
// bdr: BDmat rows in Bt layout for the BDW GEMM.
// bdr[b*256 + n][k] = (n>>5==k>>5) ? KV[b][n>>5][n&31][k&31] : 0
// ---------------------------------------------------------------------------
__global__ __launch_bounds__(256)
void bdr_build(const float* __restrict__ KV, u16* __restrict__ bdr)
{
    int idx = blockIdx.x * 256 + threadIdx.x;      // 0 .. 4*256*256-1
    int b = idx >> 16;
    int n = (idx >> 8) & 255;
    int k = idx & 255;
    float v = ((n >> 5) == (k >> 5))
            ? KV[(((size_t)b * N_HEAD + (n >> 5)) * D_H + (n & 31)) * D_H + (k & 31)]
            : 0.f;
    bdr[idx] = f2bf(v);
}

// ---------------------------------------------------------------------------
// attn_z: q[tok][c] *= L / (q[tok] . Ksum_head(c) + eps), in place.
// One wave per token; 8 lanes (32 elems) per head; shfl_xor(1,2,4) reduce.
// ---------------------------------------------------------------------------
#define NT_TOK 32
__global__ __launch_bounds__(256)
void attn_z(u16* __restrict__ q, const float* __restrict__ Ksum)
{
    const int t = threadIdx.x;
    const int w = t >> 6, lane = t & 63;
    const int tok0 = blockIdx.x * NT_TOK;
    const int n = tok0 / L_SEQ;
    float4 ks = *(const float4*)&Ksum[n * C_DIM + lane * 4];

    for (int i = 0; i < NT_TOK; i += 4) {
        int tok = tok0 + i + w;
        u16* qp = q + (size_t)tok * C_DIM + lane * 4;
        uint2 qu = *(const uint2*)qp;
        float q0 = bf2f(qu.x & 0xffff), q1 = bf2f(qu.x >> 16);
        float q2 = bf2f(qu.y & 0xffff), q3 = bf2f(qu.y >> 16);
        float p = q0 * ks.x + q1 * ks.y + q2 * ks.z + q3 * ks.w;
        p += __shfl_xor(p, 1);
        p += __shfl_xor(p, 2);
        p += __shfl_xor(p, 4);
        float z = (float)L_SEQ / (p + 1e-6f);
        uint2 o;
        o.x = (u32)f2bf(q0 * z) | ((u32)f2bf(q1 * z) << 16);
        o.y = (u32)f2bf(q2 * z) | ((u32)f2bf(q3 * z) << 16);
        *(uint2*)qp = o;
    }
}

// ---------------------------------------------------------------------------
// LayerNorm rows of 256, bf16 input. FINAL: out f32 = LN + x residual.
// ---------------------------------------------------------------------------
template<bool FINAL>
__global__ __launch_bounds__(256)
void ln_rows_bf(const u16* __restrict__ X, const float* __restrict__ g,
                const float* __restrict__ b, const float* __restrict__ xres,
                void* __restrict__ Y)
{
    int row  = blockIdx.x * 4 + (threadIdx.x >> 6);
    int lane = threadIdx.x & 63;
    uint2 u = *(const uint2*)(X + (size_t)row * C_DIM + lane * 4);
    float v0 = bf2f(u.x & 0xffff), v1 = bf2f(u.x >> 16);
    float v2 = bf2f(u.y & 0xffff), v3 = bf2f(u.y >> 16);
    float s  = v0 + v1 + v2 + v3;
    float s2 = v0 * v0 + v1 * v1 + v2 * v2 + v3 * v3;
    #pragma unroll
    for (int off = 1; off < 64; off <<= 1) {
        s  += __shfl_xor(s, off);
        s2 += __shfl_xor(s2, off);
    }
    float mu  = s * (1.0f / C_DIM);
    float var = s2 * (1.0f / C_DIM) - mu * mu;
    float rstd = rsqrtf(var + 1e-5f);
    float4 gv = *(const float4*)&g[lane * 4];
    float4 bv = *(const float4*)&b[lane * 4];
    float o0 = (v0 - mu) * rstd * gv.x + bv.x;
    float o1 = (v1 - mu) * rstd * gv.y + bv.y;
    float o2 = (v2 - mu) * rstd * gv.z + bv.z;
    float o3 = (v3 - mu) * rstd * gv.w + bv.w;
    if (FINAL) {
        float4 xv = *(const float4*)&xres[(size_t)row * C_DIM + lane * 4];
        float4 o = make_float4(o0 + xv.x, o1 + xv.y, o2 + xv.z, o3 + xv.w);
        *(float4*)((float*)Y + (size_t)row * C_DIM + lane * 4) = o;
    } else {
        uint2 o;
        o.x = (u32)f2bf(o0) | ((u32)f2bf(o1) << 16);
        o.y = (u32)f2bf(o2) | ((u32)f2bf(o3) << 16);
        *(uint2*)((u16*)Y + (size_t)row * C_DIM + lane * 4) = o;
    }
}

// ---------------------------------------------------------------------------
extern "C" void kernel_launch(void* const* d_in, const int* in_sizes, int n_in,
                              void* d_out, int out_size, void* d_ws, size_t ws_size,
                              hipStream_t stream)
{
    const float* x  = (const float*)d_in[0];
    const float* Wq = (const float*)d_in[1];
    const float* Wk = (const float*)d_in[2];
    const float* Wv = (const float*)d_in[3];
    const float* Wm = (const float*)d_in[4];
    const float* W1 = (const float*)d_in[5];
    const float* W2 = (const float*)d_in[6];
    const float* g1 = (const float*)d_in[7];
    const float* b1 = (const float*)d_in[8];
    const float* g2 = (const float*)d_in[9];
    const float* b2 = (const float*)d_in[10];
    float* out = (float*)d_out;

    u16* xb = (u16*)d_ws;          // slab 0
    u16* q  = xb + SLAB_E;         // slab 1  (becomes q', then h-lo)
    u16* k  = q + SLAB_E;          // slab 2  (dead after kv -> h-hi)
    u16* v  = k + SLAB_E;          // slab 3  (dead after kv -> ln1)
    u16* e  = v + SLAB_E;          // slab 4  (m1, then mlp)
    u16* ln1 = v;
    u16* m1  = e;
    u16* h   = q;                  // spans q..k (M x 512)
    u16* mlp = e;
    // weights (transposed bf16) + small buffers
    u16* wqkvt = e + SLAB_E;               // 768*256
    u16* wmt   = wqkvt + 768 * 256;        // 256*256
    u16* w1t   = wmt + 256 * 256;          // 512*512
    u16* w2t   = w1t + 512 * 512;          // 256*512
    u16* bdr   = w2t + 256 * 512;          // 4*256*256
    u16* bdwt  = bdr + (size_t)N_BATCH * 256 * 256;   // 4*256*256, layout [c][b*256+k]
    float* KV   = (float*)(bdwt + (size_t)N_BATCH * 256 * 256);
    float* Ksum = KV + (size_t)N_BATCH * N_HEAD * D_H * D_H;
    float* part = Ksum + (size_t)N_BATCH * N_HEAD * D_H;

    dim3 blk(256);
    const float invL = 1.0f / (float)L_SEQ;

    // ---- prep ----
    f32_to_bf16_k<<<2048, blk, 0, stream>>>(x, xb, (int)(SLAB_E / 8));
    w_prep<<<640, blk, 0, stream>>>(Wq, Wk, Wv, Wm, W1, W2, wqkvt, wmt, w1t, w2t);

    // ---- fused QKV projection -> dense q,k,v slabs ----
    gemm_bf16<4><<<(M_ROWS / 128) * 6, blk, 0, stream>>>(
        xb, xb, 256, 256, 256, wqkvt, 256, 0, q, 256, 256, invL, 6);

    // ---- KV reduction ----
    kv_partial<<<N_BATCH * N_HEAD * KV_SPLIT, blk, 0, stream>>>(k, v, 256, part);
    kv_final<<<N_BATCH * N_HEAD, blk, 0, stream>>>(part, KV, Ksum);

    // ---- BDW = BD @ Wm (tiny GEMM), bdwt[c][b*256+k] ----
    bdr_build<<<(N_BATCH * 256 * 256) / 256, blk, 0, stream>>>(KV, bdr);
    gemm_bf16<0><<<16, blk, 0, stream>>>(
        wmt, wmt, 256, 256, 256, bdr, 256, 0, bdwt, 1024, 256, 1.f, 8);

    // ---- q' = q * z  (in place) ----
    attn_z<<<M_ROWS / NT_TOK, blk, 0, stream>>>(q, Ksum);

    // ---- m1 = q' @ BDW_b  (replaces BD-GEMM + Wm-GEMM) ----
    gemm_bf16<0><<<(M_ROWS / 128) * 2, blk, 0, stream>>>(
        q, q, 256, 256, 256, bdwt, 1024, 256, m1, 256, 256, 1.f, 2);
    ln_rows_bf<false><<<M_ROWS / 4, blk, 0, stream>>>(m1, g1, b1, nullptr, (void*)ln1);

    // ---- MLP ----
    gemm_bf16<3><<<(M_ROWS / 128) * 4, blk, 0, stream>>>(
        xb, ln1, 256, 256, 256, w1t, 512, 0, h, 512, 512, 1.f, 4);
    gemm_bf16<0><<<(M_ROWS / 128) * 2, blk, 0, stream>>>(
        h, h, 512, 512, 512, w2t, 512, 0, mlp, 256, 512, 1.f, 2);

    // ---- LN2 + residual ----
    ln_rows_bf<true><<<M_ROWS / 4, blk, 0, stream>>>(mlp, g2, b2, x, out);
}